// Round 1
// baseline (277.618 us; speedup 1.0000x reference)
//
#include <hip/hip_runtime.h>

#define CCC_EPS 1e-8

// One block per row. Block = 1024 threads (16 waves). Each thread strides the
// row with float4 loads accumulating 5 sums; hierarchical reduce; thread 0
// writes (1 - ccc) for the row into ws.
__global__ __launch_bounds__(1024) void ccc_row_kernel(
    const float* __restrict__ preds,
    const float* __restrict__ labels,
    float* __restrict__ row_loss,
    int T)
{
    const int b = blockIdx.x;
    const size_t base = (size_t)b * (size_t)T;
    const float4* __restrict__ p4 = (const float4*)(preds + base);
    const float4* __restrict__ l4 = (const float4*)(labels + base);
    const int n4 = T >> 2;

    float sx = 0.f, sy = 0.f, sxx = 0.f, syy = 0.f, sxy = 0.f;

    #pragma unroll 4
    for (int i = threadIdx.x; i < n4; i += 1024) {
        float4 x = p4[i];
        float4 y = l4[i];
        sx  += x.x + x.y + x.z + x.w;
        sy  += y.x + y.y + y.z + y.w;
        sxx = fmaf(x.x, x.x, sxx); sxx = fmaf(x.y, x.y, sxx);
        sxx = fmaf(x.z, x.z, sxx); sxx = fmaf(x.w, x.w, sxx);
        syy = fmaf(y.x, y.x, syy); syy = fmaf(y.y, y.y, syy);
        syy = fmaf(y.z, y.z, syy); syy = fmaf(y.w, y.w, syy);
        sxy = fmaf(x.x, y.x, sxy); sxy = fmaf(x.y, y.y, sxy);
        sxy = fmaf(x.z, y.z, sxy); sxy = fmaf(x.w, y.w, sxy);
    }

    // wave (64-lane) reduction
    #pragma unroll
    for (int off = 32; off > 0; off >>= 1) {
        sx  += __shfl_down(sx,  off);
        sy  += __shfl_down(sy,  off);
        sxx += __shfl_down(sxx, off);
        syy += __shfl_down(syy, off);
        sxy += __shfl_down(sxy, off);
    }

    __shared__ float red[16][5];
    const int wave = threadIdx.x >> 6;
    const int lane = threadIdx.x & 63;
    if (lane == 0) {
        red[wave][0] = sx;  red[wave][1] = sy;  red[wave][2] = sxx;
        red[wave][3] = syy; red[wave][4] = sxy;
    }
    __syncthreads();

    if (threadIdx.x == 0) {
        double tsx = 0, tsy = 0, tsxx = 0, tsyy = 0, tsxy = 0;
        #pragma unroll
        for (int w = 0; w < 16; ++w) {
            tsx  += red[w][0];
            tsy  += red[w][1];
            tsxx += red[w][2];
            tsyy += red[w][3];
            tsxy += red[w][4];
        }
        const double inv = 1.0 / (double)T;
        const double mx = tsx * inv;
        const double my = tsy * inv;
        const double vx = tsxx * inv - mx * mx;
        const double vy = tsyy * inv - my * my;
        const double cov = tsxy * inv - mx * my;
        const double d = mx - my;
        const double ccc = 2.0 * cov / (vx + vy + d * d + CCC_EPS);
        row_loss[b] = (float)(1.0 - ccc);
    }
}

// Reduce B per-row losses -> scalar mean. Single block.
__global__ __launch_bounds__(512) void ccc_final_kernel(
    const float* __restrict__ row_loss,
    float* __restrict__ out,
    int B)
{
    float s = 0.f;
    for (int i = threadIdx.x; i < B; i += 512) s += row_loss[i];
    #pragma unroll
    for (int off = 32; off > 0; off >>= 1) s += __shfl_down(s, off);

    __shared__ float red[8];
    const int wave = threadIdx.x >> 6;
    const int lane = threadIdx.x & 63;
    if (lane == 0) red[wave] = s;
    __syncthreads();
    if (threadIdx.x == 0) {
        float t = 0.f;
        #pragma unroll
        for (int w = 0; w < 8; ++w) t += red[w];
        out[0] = t / (float)B;
    }
}

extern "C" void kernel_launch(void* const* d_in, const int* in_sizes, int n_in,
                              void* d_out, int out_size, void* d_ws, size_t ws_size,
                              hipStream_t stream) {
    const float* preds  = (const float*)d_in[0];
    const float* labels = (const float*)d_in[1];
    float* out = (float*)d_out;

    const int T = 65536;
    const int B = in_sizes[0] / T;   // 512

    float* row_loss = (float*)d_ws;  // B floats of scratch

    ccc_row_kernel<<<B, 1024, 0, stream>>>(preds, labels, row_loss, T);
    ccc_final_kernel<<<1, 512, 0, stream>>>(row_loss, out, B);
}

// Round 2
// 271.409 us; speedup vs baseline: 1.0229x; 1.0229x over previous
//
#include <hip/hip_runtime.h>

#define CCC_EPS 1e-8
#define SEGS 8          // segments per row
#define K_UNROLL 8      // float4 loads per array per thread

// Grid: (SEGS, B). Block = 256 threads (4 waves). Each block reduces a
// T/SEGS-element segment of one row into 5 partial sums, written to ws.
// Per thread: 8 float4 from each array, loaded into register batches first
// (16 independent loads in flight) then consumed.
__global__ __launch_bounds__(256) void ccc_partial_kernel(
    const float* __restrict__ preds,
    const float* __restrict__ labels,
    float* __restrict__ partial,   // [B*SEGS*5]
    int T)
{
    const int seg = blockIdx.x;
    const int row = blockIdx.y;
    const int seg4 = (T >> 2) / SEGS;                 // float4 per segment (2048)
    const size_t base4 = (size_t)row * (size_t)(T >> 2) + (size_t)seg * seg4;
    const float4* __restrict__ p4 = (const float4*)preds + base4;
    const float4* __restrict__ l4 = (const float4*)labels + base4;

    float4 xs[K_UNROLL], ys[K_UNROLL];
    #pragma unroll
    for (int k = 0; k < K_UNROLL; ++k) {
        xs[k] = p4[threadIdx.x + k * 256];
        ys[k] = l4[threadIdx.x + k * 256];
    }

    float sx = 0.f, sy = 0.f, sxx = 0.f, syy = 0.f, sxy = 0.f;
    #pragma unroll
    for (int k = 0; k < K_UNROLL; ++k) {
        float4 x = xs[k];
        float4 y = ys[k];
        sx  += x.x + x.y + x.z + x.w;
        sy  += y.x + y.y + y.z + y.w;
        sxx = fmaf(x.x, x.x, sxx); sxx = fmaf(x.y, x.y, sxx);
        sxx = fmaf(x.z, x.z, sxx); sxx = fmaf(x.w, x.w, sxx);
        syy = fmaf(y.x, y.x, syy); syy = fmaf(y.y, y.y, syy);
        syy = fmaf(y.z, y.z, syy); syy = fmaf(y.w, y.w, syy);
        sxy = fmaf(x.x, y.x, sxy); sxy = fmaf(x.y, y.y, sxy);
        sxy = fmaf(x.z, y.z, sxy); sxy = fmaf(x.w, y.w, sxy);
    }

    // 64-lane wave reduction
    #pragma unroll
    for (int off = 32; off > 0; off >>= 1) {
        sx  += __shfl_down(sx,  off);
        sy  += __shfl_down(sy,  off);
        sxx += __shfl_down(sxx, off);
        syy += __shfl_down(syy, off);
        sxy += __shfl_down(sxy, off);
    }

    __shared__ float red[4][5];
    const int wave = threadIdx.x >> 6;
    const int lane = threadIdx.x & 63;
    if (lane == 0) {
        red[wave][0] = sx;  red[wave][1] = sy;  red[wave][2] = sxx;
        red[wave][3] = syy; red[wave][4] = sxy;
    }
    __syncthreads();

    if (threadIdx.x == 0) {
        float t0 = red[0][0] + red[1][0] + red[2][0] + red[3][0];
        float t1 = red[0][1] + red[1][1] + red[2][1] + red[3][1];
        float t2 = red[0][2] + red[1][2] + red[2][2] + red[3][2];
        float t3 = red[0][3] + red[1][3] + red[2][3] + red[3][3];
        float t4 = red[0][4] + red[1][4] + red[2][4] + red[3][4];
        float* dst = partial + ((size_t)row * SEGS + seg) * 5;
        dst[0] = t0; dst[1] = t1; dst[2] = t2; dst[3] = t3; dst[4] = t4;
    }
}

// Single block: one thread per row combines its SEGS partials in double,
// computes (1 - ccc), then block-reduces the mean.
__global__ __launch_bounds__(512) void ccc_final_kernel(
    const float* __restrict__ partial,
    float* __restrict__ out,
    int B, int T)
{
    float loss_sum = 0.f;
    for (int b = threadIdx.x; b < B; b += 512) {
        double tsx = 0, tsy = 0, tsxx = 0, tsyy = 0, tsxy = 0;
        const float* src = partial + (size_t)b * SEGS * 5;
        #pragma unroll
        for (int s = 0; s < SEGS; ++s) {
            tsx  += src[s * 5 + 0];
            tsy  += src[s * 5 + 1];
            tsxx += src[s * 5 + 2];
            tsyy += src[s * 5 + 3];
            tsxy += src[s * 5 + 4];
        }
        const double inv = 1.0 / (double)T;
        const double mx = tsx * inv;
        const double my = tsy * inv;
        const double vx = tsxx * inv - mx * mx;
        const double vy = tsyy * inv - my * my;
        const double cov = tsxy * inv - mx * my;
        const double d = mx - my;
        const double ccc = 2.0 * cov / (vx + vy + d * d + CCC_EPS);
        loss_sum += (float)(1.0 - ccc);
    }

    #pragma unroll
    for (int off = 32; off > 0; off >>= 1) loss_sum += __shfl_down(loss_sum, off);

    __shared__ float red[8];
    const int wave = threadIdx.x >> 6;
    const int lane = threadIdx.x & 63;
    if (lane == 0) red[wave] = loss_sum;
    __syncthreads();
    if (threadIdx.x == 0) {
        float t = 0.f;
        #pragma unroll
        for (int w = 0; w < 8; ++w) t += red[w];
        out[0] = t / (float)B;
    }
}

extern "C" void kernel_launch(void* const* d_in, const int* in_sizes, int n_in,
                              void* d_out, int out_size, void* d_ws, size_t ws_size,
                              hipStream_t stream) {
    const float* preds  = (const float*)d_in[0];
    const float* labels = (const float*)d_in[1];
    float* out = (float*)d_out;

    const int T = 65536;
    const int B = in_sizes[0] / T;   // 512

    float* partial = (float*)d_ws;   // B*SEGS*5 floats

    dim3 grid(SEGS, B);
    ccc_partial_kernel<<<grid, 256, 0, stream>>>(preds, labels, partial, T);
    ccc_final_kernel<<<1, 512, 0, stream>>>(partial, out, B, T);
}

// Round 4
// 250.443 us; speedup vs baseline: 1.1085x; 1.0837x over previous
//
#include <hip/hip_runtime.h>

#define CCC_EPS 1e-8
#define SEGS 4           // blocks per row
#define TPB 256
#define PER_THREAD 16    // vec4 per array per thread (SEGS*TPB*PER_THREAD*4 == T)

typedef float floatx4 __attribute__((ext_vector_type(4)));  // native vector: OK for nontemporal builtins

// Grid: 2048 blocks (= 8 blocks/CU on 256 CUs -> 32 waves/CU). Each block
// reduces a contiguous 4096-vec4 segment of one row. Nontemporal loads
// bypass L3 allocation (working set == L3 capacity -> alloc/evict thrash).
__global__ __launch_bounds__(TPB, 8) void ccc_partial_kernel(
    const float* __restrict__ preds,
    const float* __restrict__ labels,
    float* __restrict__ partial,   // [B*SEGS*5]
    int T)
{
    const int seg = blockIdx.x & (SEGS - 1);
    const int row = blockIdx.x >> 2;                 // SEGS == 4
    const int seg4 = (T >> 2) / SEGS;                // 4096 vec4
    const size_t base4 = (size_t)row * (size_t)(T >> 2) + (size_t)seg * seg4;
    const floatx4* __restrict__ p4 = (const floatx4*)preds + base4;
    const floatx4* __restrict__ l4 = (const floatx4*)labels + base4;

    float sx = 0.f, sy = 0.f, sxx = 0.f, syy = 0.f, sxy = 0.f;

    #pragma unroll 8
    for (int k = 0; k < PER_THREAD; ++k) {
        const int i = threadIdx.x + k * TPB;
        floatx4 x = __builtin_nontemporal_load(&p4[i]);
        floatx4 y = __builtin_nontemporal_load(&l4[i]);
        sx  += x.x + x.y + x.z + x.w;
        sy  += y.x + y.y + y.z + y.w;
        sxx = fmaf(x.x, x.x, sxx); sxx = fmaf(x.y, x.y, sxx);
        sxx = fmaf(x.z, x.z, sxx); sxx = fmaf(x.w, x.w, sxx);
        syy = fmaf(y.x, y.x, syy); syy = fmaf(y.y, y.y, syy);
        syy = fmaf(y.z, y.z, syy); syy = fmaf(y.w, y.w, syy);
        sxy = fmaf(x.x, y.x, sxy); sxy = fmaf(x.y, y.y, sxy);
        sxy = fmaf(x.z, y.z, sxy); sxy = fmaf(x.w, y.w, sxy);
    }

    // 64-lane wave reduction
    #pragma unroll
    for (int off = 32; off > 0; off >>= 1) {
        sx  += __shfl_down(sx,  off);
        sy  += __shfl_down(sy,  off);
        sxx += __shfl_down(sxx, off);
        syy += __shfl_down(syy, off);
        sxy += __shfl_down(sxy, off);
    }

    __shared__ float red[4][5];
    const int wave = threadIdx.x >> 6;
    const int lane = threadIdx.x & 63;
    if (lane == 0) {
        red[wave][0] = sx;  red[wave][1] = sy;  red[wave][2] = sxx;
        red[wave][3] = syy; red[wave][4] = sxy;
    }
    __syncthreads();

    if (threadIdx.x == 0) {
        float t0 = red[0][0] + red[1][0] + red[2][0] + red[3][0];
        float t1 = red[0][1] + red[1][1] + red[2][1] + red[3][1];
        float t2 = red[0][2] + red[1][2] + red[2][2] + red[3][2];
        float t3 = red[0][3] + red[1][3] + red[2][3] + red[3][3];
        float t4 = red[0][4] + red[1][4] + red[2][4] + red[3][4];
        float* dst = partial + ((size_t)row * SEGS + seg) * 5;
        dst[0] = t0; dst[1] = t1; dst[2] = t2; dst[3] = t3; dst[4] = t4;
    }
}

// Single block: one thread per row combines its SEGS partials in double,
// computes (1 - ccc), then block-reduces the mean.
__global__ __launch_bounds__(512) void ccc_final_kernel(
    const float* __restrict__ partial,
    float* __restrict__ out,
    int B, int T)
{
    float loss_sum = 0.f;
    for (int b = threadIdx.x; b < B; b += 512) {
        double tsx = 0, tsy = 0, tsxx = 0, tsyy = 0, tsxy = 0;
        const float* src = partial + (size_t)b * SEGS * 5;
        #pragma unroll
        for (int s = 0; s < SEGS; ++s) {
            tsx  += src[s * 5 + 0];
            tsy  += src[s * 5 + 1];
            tsxx += src[s * 5 + 2];
            tsyy += src[s * 5 + 3];
            tsxy += src[s * 5 + 4];
        }
        const double inv = 1.0 / (double)T;
        const double mx = tsx * inv;
        const double my = tsy * inv;
        const double vx = tsxx * inv - mx * mx;
        const double vy = tsyy * inv - my * my;
        const double cov = tsxy * inv - mx * my;
        const double d = mx - my;
        const double ccc = 2.0 * cov / (vx + vy + d * d + CCC_EPS);
        loss_sum += (float)(1.0 - ccc);
    }

    #pragma unroll
    for (int off = 32; off > 0; off >>= 1) loss_sum += __shfl_down(loss_sum, off);

    __shared__ float red[8];
    const int wave = threadIdx.x >> 6;
    const int lane = threadIdx.x & 63;
    if (lane == 0) red[wave] = loss_sum;
    __syncthreads();
    if (threadIdx.x == 0) {
        float t = 0.f;
        #pragma unroll
        for (int w = 0; w < 8; ++w) t += red[w];
        out[0] = t / (float)B;
    }
}

extern "C" void kernel_launch(void* const* d_in, const int* in_sizes, int n_in,
                              void* d_out, int out_size, void* d_ws, size_t ws_size,
                              hipStream_t stream) {
    const float* preds  = (const float*)d_in[0];
    const float* labels = (const float*)d_in[1];
    float* out = (float*)d_out;

    const int T = 65536;
    const int B = in_sizes[0] / T;   // 512

    float* partial = (float*)d_ws;   // B*SEGS*5 floats

    ccc_partial_kernel<<<B * SEGS, TPB, 0, stream>>>(preds, labels, partial, T);
    ccc_final_kernel<<<1, 512, 0, stream>>>(partial, out, B, T);
}